// Round 2
// baseline (232.782 us; speedup 1.0000x reference)
//
#include <hip/hip_runtime.h>

#define BLOCK 256
#define GRID 2048

__global__ __launch_bounds__(BLOCK) void loss_partial_kernel(
    const float* __restrict__ pred,   // (N,2) row-major
    const int* __restrict__ target,   // (N,)
    float* __restrict__ partials,     // (GRID,)
    int n4)                           // N/4 groups of 4 rows
{
    const float4* __restrict__ pred4 = reinterpret_cast<const float4*>(pred);
    const int4* __restrict__ tgt4 = reinterpret_cast<const int4*>(target);

    float acc = 0.0f;
    const int stride = gridDim.x * blockDim.x;
    for (int i = blockIdx.x * blockDim.x + threadIdx.x; i < n4; i += stride) {
        // 4 rows: pred rows 4i..4i+3 live in float4s 2i and 2i+1
        float4 pa = pred4[2 * i];       // rows 4i   (x,y), 4i+1 (z,w)
        float4 pb = pred4[2 * i + 1];   // rows 4i+2 (x,y), 4i+3 (z,w)
        int4 t = tgt4[i];

        float p0[4] = {pa.x, pa.z, pb.x, pb.z};
        float p1[4] = {pa.y, pa.w, pb.y, pb.w};
        int tt[4] = {t.x, t.y, t.z, t.w};

#pragma unroll
        for (int k = 0; k < 4; ++k) {
            bool z = (tt[k] == 0);
            float a = z ? p0[k] : p1[k];   // prob of the correct class
            float b = z ? p1[k] : p0[k];   // prob of the wrong class
            float d = 1.0f - a;
            float s = fmaf(d, d, b * b);
            s += (a < b) ? 2.0f : 0.0f;
            acc += s;
        }
    }

    // wave64 butterfly reduce
#pragma unroll
    for (int off = 32; off > 0; off >>= 1)
        acc += __shfl_down(acc, off, 64);

    __shared__ float wsum[BLOCK / 64];
    const int lane = threadIdx.x & 63;
    const int wid = threadIdx.x >> 6;
    if (lane == 0) wsum[wid] = acc;
    __syncthreads();
    if (threadIdx.x == 0) {
        float s = 0.0f;
#pragma unroll
        for (int w = 0; w < BLOCK / 64; ++w) s += wsum[w];
        partials[blockIdx.x] = s;
    }
}

__global__ __launch_bounds__(BLOCK) void loss_final_kernel(
    const float* __restrict__ partials, float* __restrict__ out,
    int nparts, float inv_n)
{
    float acc = 0.0f;
    for (int i = threadIdx.x; i < nparts; i += BLOCK)
        acc += partials[i];

#pragma unroll
    for (int off = 32; off > 0; off >>= 1)
        acc += __shfl_down(acc, off, 64);

    __shared__ float wsum[BLOCK / 64];
    const int lane = threadIdx.x & 63;
    const int wid = threadIdx.x >> 6;
    if (lane == 0) wsum[wid] = acc;
    __syncthreads();
    if (threadIdx.x == 0) {
        float s = 0.0f;
#pragma unroll
        for (int w = 0; w < BLOCK / 64; ++w) s += wsum[w];
        out[0] = s * inv_n;
    }
}

extern "C" void kernel_launch(void* const* d_in, const int* in_sizes, int n_in,
                              void* d_out, int out_size, void* d_ws, size_t ws_size,
                              hipStream_t stream) {
    const float* pred = (const float*)d_in[0];
    const int* target = (const int*)d_in[1];
    float* out = (float*)d_out;
    float* partials = (float*)d_ws;

    // pred is (N,2) -> in_sizes[0] == 2N; target is (N,) -> in_sizes[1] == N.
    int n = in_sizes[1];
    if (n * 2 != in_sizes[0]) n = in_sizes[0] / 2;   // defensive fallback
    const int n4 = n / 4;                            // N = 16777216, multiple of 4

    loss_partial_kernel<<<GRID, BLOCK, 0, stream>>>(pred, target, partials, n4);
    loss_final_kernel<<<1, BLOCK, 0, stream>>>(partials, out, GRID, 1.0f / (float)n);
}